// Round 10
// baseline (111.363 us; speedup 1.0000x reference)
//
#include <hip/hip_runtime.h>
#include <math.h>

#define Bb 2
#define Lq 512
#define CS 384
#define CZ 128
#define Hh 8
#define HD 16
#define NEG_MAX -3.4028234663852886e38f

typedef float f2_t __attribute__((ext_vector_type(2)));

__device__ inline float wave_reduce_sum(float v) {
    #pragma unroll
    for (int off = 32; off > 0; off >>= 1) v += __shfl_xor(v, off, 64);
    return v;
}
__device__ inline float wave_reduce_max(float v) {
    #pragma unroll
    for (int off = 32; off > 0; off >>= 1) v = fmaxf(v, __shfl_xor(v, off, 64));
    return v;
}
__device__ inline void wave_reduce_sum2(float& a, float& b) {
    #pragma unroll
    for (int off = 32; off > 0; off >>= 1) {
        a += __shfl_xor(a, off, 64);
        b += __shfl_xor(b, off, 64);
    }
}

// Fused: x = rmsnorm(s @ W_s^T, g_s) in LDS, qk = x @ W_qk^T + RoPE. (round-7 proven)
__global__ __launch_bounds__(256) void k_proj(const float* __restrict__ s,
        const float* __restrict__ W_s, const float* __restrict__ g_s,
        const float* __restrict__ W_qk, float* __restrict__ qk_ws) {
    int blk = blockIdx.x;            // rows blk*4 .. blk*4+3
    int t = threadIdx.x;             // 0..255
    __shared__ float s_lds[4*CS];
    __shared__ float x_lds[4*CZ];
    __shared__ float qkrow[4][2*CZ];
    __shared__ float red[4][2];
    size_t base = (size_t)blk * 4 * CS;
    for (int i = t; i < 4*CS; i += 256) s_lds[i] = s[base + i];
    __syncthreads();

    int c = t & 127, rpair = t >> 7;
    float aA = 0.f, aB = 0.f;
    {
        const float4* w4 = (const float4*)(W_s + (size_t)c * CS);
        const float4* sA = (const float4*)(s_lds + (2*rpair    )*CS);
        const float4* sB = (const float4*)(s_lds + (2*rpair + 1)*CS);
        #pragma unroll 4
        for (int i = 0; i < CS/4; ++i) {
            float4 w = w4[i];
            float4 vA = sA[i], vB = sB[i];
            aA += w.x*vA.x + w.y*vA.y + w.z*vA.z + w.w*vA.w;
            aB += w.x*vB.x + w.y*vB.y + w.z*vB.z + w.w*vB.w;
        }
    }
    {
        float sA = aA*aA, sB = aB*aB;
        wave_reduce_sum2(sA, sB);
        int lane = t & 63, wid = t >> 6;
        if (lane == 0) { red[wid][0] = sA; red[wid][1] = sB; }
    }
    __syncthreads();
    {
        float g = g_s[c];
        int w0 = (rpair == 0) ? 0 : 2;
        float tA = red[w0][0] + red[w0+1][0];
        float tB = red[w0][1] + red[w0+1][1];
        x_lds[(2*rpair  )*CZ + c] = aA * rsqrtf(tA*(1.f/CZ) + 1e-5f) * g;
        x_lds[(2*rpair+1)*CZ + c] = aB * rsqrtf(tB*(1.f/CZ) + 1e-5f) * g;
    }
    __syncthreads();

    {
        const float4* w4 = (const float4*)(W_qk + (size_t)t * CZ);
        const float4* x0 = (const float4*)(x_lds);
        const float4* x1 = (const float4*)(x_lds + CZ);
        const float4* x2 = (const float4*)(x_lds + 2*CZ);
        const float4* x3 = (const float4*)(x_lds + 3*CZ);
        float q0=0.f, q1=0.f, q2=0.f, q3=0.f;
        #pragma unroll 4
        for (int i = 0; i < CZ/4; ++i) {
            float4 w = w4[i];
            float4 v0=x0[i], v1=x1[i], v2=x2[i], v3=x3[i];
            q0 += w.x*v0.x + w.y*v0.y + w.z*v0.z + w.w*v0.w;
            q1 += w.x*v1.x + w.y*v1.y + w.z*v1.z + w.w*v1.w;
            q2 += w.x*v2.x + w.y*v2.y + w.z*v2.z + w.w*v2.w;
            q3 += w.x*v3.x + w.y*v3.y + w.z*v3.z + w.w*v3.w;
        }
        qkrow[0][t]=q0; qkrow[1][t]=q1; qkrow[2][t]=q2; qkrow[3][t]=q3;
    }
    __syncthreads();
    {
        int half = t >> 7, within = t & 127, h = within >> 4, dd = within & 15, d = dd >> 1;
        int row0 = blk * 4;
        int b = row0 >> 9;
        float inv = exp2f(-(float)(2*d) * (1.f/16.f) * 13.287712379549449f);
        #pragma unroll
        for (int r = 0; r < 4; ++r) {
            int l = (row0 + r) & (Lq - 1);
            float ang = (float)l * inv;
            float cv = cosf(ang), sn = sinf(ang);
            float xr = qkrow[r][t & ~1];
            float xi = qkrow[r][t | 1];
            float outv = (dd & 1) ? (xr*sn + xi*cv) : (xr*cv - xi*sn);
            size_t idx = ((((size_t)half*Bb + b)*Hh + h)*Lq + l)*HD + dd;
            qk_ws[idx] = outv;
        }
    }
}

// k_soft: per (b,l) block — softmax all 8 heads + Gram sc; write probs TRANSPOSED
// p_ws[R][8] (R = bl*512+m) and sc_ws[R]. Plain stores (keep L2-resident).
__global__ __launch_bounds__(512) void k_soft(const float* __restrict__ qk_ws,
        const int* __restrict__ mask, const float* __restrict__ W_o,
        float* __restrict__ p_ws, float* __restrict__ sc_ws) {
    int row = blockIdx.x;            // b*512 + l
    int l = row & (Lq - 1);
    int b = row >> 9;
    int t = threadIdx.x;
    int w = t >> 6, lane = t & 63;
    __shared__ float p_lds[Hh][Lq];
    __shared__ float q_lds[CZ];
    __shared__ float g_lds[Hh*Hh];
    if (t < CZ) {
        int qh = t >> 4, dd = t & 15;
        q_lds[t] = qk_ws[(((size_t)b*Hh + qh)*Lq + l)*HD + dd];
    }
    // Gram: wave w computes G[w][k]
    {
        int k = lane & 7, cg = lane >> 3;
        float partial = 0.f;
        #pragma unroll
        for (int cc = 0; cc < 16; ++cc) {
            int cidx = cg*16 + cc;
            partial += W_o[cidx*Hh + w] * W_o[cidx*Hh + k];
        }
        partial += __shfl_xor(partial, 8, 64);
        partial += __shfl_xor(partial, 16, 64);
        partial += __shfl_xor(partial, 32, 64);
        if (lane < 8) g_lds[w*Hh + lane] = partial;
    }
    int maskL = mask[b*Lq + l];
    __syncthreads();

    // phase 1: wave w == head h softmax row
    {
        int h = w;
        const float* kbase = qk_ws + ((((size_t)Bb + b)*Hh + h)*Lq)*HD;
        float q[HD];
        #pragma unroll
        for (int d = 0; d < HD; ++d) q[d] = q_lds[h*HD + d];
        float sv[8];
        float mx = NEG_MAX;
        #pragma unroll
        for (int i = 0; i < 8; ++i) {
            int m = i*64 + lane;
            const float4* k4 = (const float4*)(kbase + (size_t)m * HD);
            float4 k0=k4[0], k1=k4[1], k2=k4[2], k3=k4[3];
            float acc = q[0]*k0.x + q[1]*k0.y + q[2]*k0.z + q[3]*k0.w
                      + q[4]*k1.x + q[5]*k1.y + q[6]*k1.z + q[7]*k1.w
                      + q[8]*k2.x + q[9]*k2.y + q[10]*k2.z + q[11]*k2.w
                      + q[12]*k3.x + q[13]*k3.y + q[14]*k3.z + q[15]*k3.w;
            int pm = maskL & mask[b*Lq + m];
            sv[i] = pm ? acc*0.25f : NEG_MAX;
            mx = fmaxf(mx, sv[i]);
        }
        mx = wave_reduce_max(mx);
        float e[8];
        float sum = 0.f;
        #pragma unroll
        for (int i = 0; i < 8; ++i) { e[i] = __expf(sv[i]-mx); sum += e[i]; }
        sum = wave_reduce_sum(sum);
        float inv = 1.f / sum;
        #pragma unroll
        for (int i = 0; i < 8; ++i) p_lds[h][i*64+lane] = e[i]*inv;
    }
    __syncthreads();

    // merged phase 1.5: thread t = row m: read p[8], Gram ss -> sc, write p+sc
    {
        float p[8];
        #pragma unroll
        for (int k = 0; k < 8; ++k) p[k] = p_lds[k][t];
        float ss = 0.f;
        #pragma unroll
        for (int j = 0; j < 8; ++j) {
            float4 gA = *(const float4*)&g_lds[j*8];
            float4 gB = *(const float4*)&g_lds[j*8 + 4];
            float qj = gA.x*p[0] + gA.y*p[1] + gA.z*p[2] + gA.w*p[3]
                     + gB.x*p[4] + gB.y*p[5] + gB.z*p[6] + gB.w*p[7];
            ss += p[j]*qj;
        }
        size_t R = (size_t)row * Lq + t;
        sc_ws[R] = rsqrtf(ss*(1.f/CZ) + 1e-5f);
        float4* pd = (float4*)(p_ws + R*8);
        float4 lo; lo.x=p[0]; lo.y=p[1]; lo.z=p[2]; lo.w=p[3];
        float4 hi; hi.x=p[4]; hi.y=p[5]; hi.z=p[6]; hi.w=p[7];
        pd[0] = lo; pd[1] = hi;
    }
}

// k_out: pure streaming output. Block = 128 consecutive output rows; wave = 32 rows.
// Per 2 rows: 5 broadcast loads (p 64B + sc 8B), 16 packed FMA, 2 nt stores.
__global__ __launch_bounds__(256) void k_out(const float* __restrict__ p_ws,
        const float* __restrict__ sc_ws, const float* __restrict__ W_o,
        const float* __restrict__ g_z, float* __restrict__ out) {
    int t = threadIdx.x;
    int w = t >> 6, lane = t & 63;
    int r0 = blockIdx.x * 128 + w * 32;   // 32 rows per wave
    int c0 = lane * 2;
    f2_t wv[Hh];
    {
        const float4* wp = (const float4*)(W_o + (size_t)c0 * Hh);
        float4 A0=wp[0], A1=wp[1], A2=wp[2], A3=wp[3];
        wv[0].x=A0.x; wv[1].x=A0.y; wv[2].x=A0.z; wv[3].x=A0.w;
        wv[4].x=A1.x; wv[5].x=A1.y; wv[6].x=A1.z; wv[7].x=A1.w;
        wv[0].y=A2.x; wv[1].y=A2.y; wv[2].y=A2.z; wv[3].y=A2.w;
        wv[4].y=A3.x; wv[5].y=A3.y; wv[6].y=A3.z; wv[7].y=A3.w;
    }
    f2_t gz2; gz2.x = g_z[c0]; gz2.y = g_z[c0 + 1];
    const float4* pb  = (const float4*)(p_ws + (size_t)r0 * 8);
    const float*  scb = sc_ws + r0;
    float* obase = out + (size_t)r0 * CZ + c0;
    #pragma unroll 2
    for (int i = 0; i < 16; ++i) {
        float4 pA = pb[i*4+0], pB = pb[i*4+1];   // row r0+2i   (h0-3, h4-7)
        float4 pC = pb[i*4+2], pD = pb[i*4+3];   // row r0+2i+1
        float s0 = scb[2*i], s1 = scb[2*i+1];
        f2_t a0 = {0.f, 0.f}, a1 = {0.f, 0.f};
        a0 += pA.x*wv[0]; a0 += pA.y*wv[1]; a0 += pA.z*wv[2]; a0 += pA.w*wv[3];
        a0 += pB.x*wv[4]; a0 += pB.y*wv[5]; a0 += pB.z*wv[6]; a0 += pB.w*wv[7];
        a1 += pC.x*wv[0]; a1 += pC.y*wv[1]; a1 += pC.z*wv[2]; a1 += pC.w*wv[3];
        a1 += pD.x*wv[4]; a1 += pD.y*wv[5]; a1 += pD.z*wv[6]; a1 += pD.w*wv[7];
        a0 *= s0 * gz2; a1 *= s1 * gz2;
        __builtin_nontemporal_store(a0, (f2_t*)(obase + (size_t)(2*i  )*CZ));
        __builtin_nontemporal_store(a1, (f2_t*)(obase + (size_t)(2*i+1)*CZ));
    }
}

// Fallback (round-7 proven k_attn) if ws too small for the split path.
__global__ __launch_bounds__(512) void k_attn_fb(const float* __restrict__ qk_ws,
        const int* __restrict__ mask, const float* __restrict__ W_o,
        const float* __restrict__ g_z, float* __restrict__ out) {
    int row = blockIdx.x;
    int l = row & (Lq - 1);
    int b = row >> 9;
    int t = threadIdx.x;
    int w = t >> 6, lane = t & 63;
    __shared__ float p_lds[Hh][Lq];
    __shared__ float q_lds[CZ];
    __shared__ float g_lds[Hh*Hh];
    __shared__ float sc_lds[Lq];
    if (t < CZ) {
        int qh = t >> 4, dd = t & 15;
        q_lds[t] = qk_ws[(((size_t)b*Hh + qh)*Lq + l)*HD + dd];
    }
    {
        int k = lane & 7, cg = lane >> 3;
        float partial = 0.f;
        #pragma unroll
        for (int cc = 0; cc < 16; ++cc) {
            int cidx = cg*16 + cc;
            partial += W_o[cidx*Hh + w] * W_o[cidx*Hh + k];
        }
        partial += __shfl_xor(partial, 8, 64);
        partial += __shfl_xor(partial, 16, 64);
        partial += __shfl_xor(partial, 32, 64);
        if (lane < 8) g_lds[w*Hh + lane] = partial;
    }
    int maskL = mask[b*Lq + l];
    __syncthreads();
    {
        int h = w;
        const float* kbase = qk_ws + ((((size_t)Bb + b)*Hh + h)*Lq)*HD;
        float q[HD];
        #pragma unroll
        for (int d = 0; d < HD; ++d) q[d] = q_lds[h*HD + d];
        float sv[8];
        float mx = NEG_MAX;
        #pragma unroll
        for (int i = 0; i < 8; ++i) {
            int m = i*64 + lane;
            const float4* k4 = (const float4*)(kbase + (size_t)m * HD);
            float4 k0=k4[0], k1=k4[1], k2=k4[2], k3=k4[3];
            float acc = q[0]*k0.x + q[1]*k0.y + q[2]*k0.z + q[3]*k0.w
                      + q[4]*k1.x + q[5]*k1.y + q[6]*k1.z + q[7]*k1.w
                      + q[8]*k2.x + q[9]*k2.y + q[10]*k2.z + q[11]*k2.w
                      + q[12]*k3.x + q[13]*k3.y + q[14]*k3.z + q[15]*k3.w;
            int pm = maskL & mask[b*Lq + m];
            sv[i] = pm ? acc*0.25f : NEG_MAX;
            mx = fmaxf(mx, sv[i]);
        }
        mx = wave_reduce_max(mx);
        float e[8];
        float sum = 0.f;
        #pragma unroll
        for (int i = 0; i < 8; ++i) { e[i] = __expf(sv[i]-mx); sum += e[i]; }
        sum = wave_reduce_sum(sum);
        float inv = 1.f / sum;
        #pragma unroll
        for (int i = 0; i < 8; ++i) p_lds[h][i*64+lane] = e[i]*inv;
    }
    __syncthreads();
    {
        float p[8];
        #pragma unroll
        for (int k = 0; k < 8; ++k) p[k] = p_lds[k][t];
        float ss = 0.f;
        #pragma unroll
        for (int j = 0; j < 8; ++j) {
            float4 gA = *(const float4*)&g_lds[j*8];
            float4 gB = *(const float4*)&g_lds[j*8 + 4];
            float qj = gA.x*p[0] + gA.y*p[1] + gA.z*p[2] + gA.w*p[3]
                     + gB.x*p[4] + gB.y*p[5] + gB.z*p[6] + gB.w*p[7];
            ss += p[j]*qj;
        }
        sc_lds[t] = rsqrtf(ss*(1.f/CZ) + 1e-5f);
    }
    int c0 = lane * 2;
    float wo0[Hh], wo1[Hh];
    {
        const float4* wp = (const float4*)(W_o + (size_t)c0 * Hh);
        float4 A0=wp[0], A1=wp[1], A2=wp[2], A3=wp[3];
        wo0[0]=A0.x; wo0[1]=A0.y; wo0[2]=A0.z; wo0[3]=A0.w;
        wo0[4]=A1.x; wo0[5]=A1.y; wo0[6]=A1.z; wo0[7]=A1.w;
        wo1[0]=A2.x; wo1[1]=A2.y; wo1[2]=A2.z; wo1[3]=A2.w;
        wo1[4]=A3.x; wo1[5]=A3.y; wo1[6]=A3.z; wo1[7]=A3.w;
    }
    float gx = g_z[c0], gy = g_z[c0 + 1];
    __syncthreads();
    float* obase = out + (size_t)row * Lq * CZ;
    #pragma unroll 1
    for (int i = 0; i < 32; ++i) {
        int m0 = i*16 + w*2;
        float2 pp[Hh];
        #pragma unroll
        for (int k = 0; k < Hh; ++k) pp[k] = *(const float2*)&p_lds[k][m0];
        float2 sc2 = *(const float2*)&sc_lds[m0];
        float a0=0.f, b0=0.f, a1=0.f, b1=0.f;
        #pragma unroll
        for (int k = 0; k < Hh; ++k) {
            a0 += pp[k].x*wo0[k]; b0 += pp[k].x*wo1[k];
            a1 += pp[k].y*wo0[k]; b1 += pp[k].y*wo1[k];
        }
        f2_t o0; o0.x = a0*sc2.x*gx; o0.y = b0*sc2.x*gy;
        f2_t o1; o1.x = a1*sc2.y*gx; o1.y = b1*sc2.y*gy;
        __builtin_nontemporal_store(o0, (f2_t*)(obase + (size_t)m0*CZ + c0));
        __builtin_nontemporal_store(o1, (f2_t*)(obase + (size_t)(m0+1)*CZ + c0));
    }
}

extern "C" void kernel_launch(void* const* d_in, const int* in_sizes, int n_in,
                              void* d_out, int out_size, void* d_ws, size_t ws_size,
                              hipStream_t stream) {
    const float* s    = (const float*)d_in[0];
    const int*   mask = (const int*)d_in[1];
    const float* W_s  = (const float*)d_in[2];
    const float* g_s  = (const float*)d_in[3];
    const float* W_qk = (const float*)d_in[4];
    const float* W_o  = (const float*)d_in[5];
    const float* g_z  = (const float*)d_in[6];
    float* out = (float*)d_out;
    float* ws  = (float*)d_ws;

    // ws layout (floats): qk_ws [0, 262144), p_ws [262144, 4456448), sc_ws [4456448, 4980736)
    float* qk_ws = ws;
    float* p_ws  = ws + 262144;
    float* sc_ws = ws + 262144 + 4194304;
    const size_t needed = (size_t)4980736 * 4;

    k_proj<<<256, 256, 0, stream>>>(s, W_s, g_s, W_qk, qk_ws);
    if (ws_size >= needed) {
        k_soft<<<Bb*Lq, 512, 0, stream>>>(qk_ws, mask, W_o, p_ws, sc_ws);
        k_out<<<4096, 256, 0, stream>>>(p_ws, sc_ws, W_o, g_z, out);
    } else {
        k_attn_fb<<<Bb*Lq, 512, 0, stream>>>(qk_ws, mask, W_o, g_z, out);
    }
}

// Round 11
// 81.273 us; speedup vs baseline: 1.3702x; 1.3702x over previous
//
#include <hip/hip_runtime.h>
#include <math.h>

#define Bb 2
#define Lq 512
#define CS 384
#define CZ 128
#define Hh 8
#define HD 16
#define NEG_MAX -3.4028234663852886e38f

typedef float f2_t __attribute__((ext_vector_type(2)));

__device__ inline float wave_reduce_sum(float v) {
    #pragma unroll
    for (int off = 32; off > 0; off >>= 1) v += __shfl_xor(v, off, 64);
    return v;
}
__device__ inline float wave_reduce_max(float v) {
    #pragma unroll
    for (int off = 32; off > 0; off >>= 1) v = fmaxf(v, __shfl_xor(v, off, 64));
    return v;
}
__device__ inline void wave_reduce_sum2(float& a, float& b) {
    #pragma unroll
    for (int off = 32; off > 0; off >>= 1) {
        a += __shfl_xor(a, off, 64);
        b += __shfl_xor(b, off, 64);
    }
}

// Fused: x = rmsnorm(s @ W_s^T, g_s) in LDS, qk = x @ W_qk^T + RoPE. (round-7 proven)
__global__ __launch_bounds__(256) void k_proj(const float* __restrict__ s,
        const float* __restrict__ W_s, const float* __restrict__ g_s,
        const float* __restrict__ W_qk, float* __restrict__ qk_ws) {
    int blk = blockIdx.x;            // rows blk*4 .. blk*4+3
    int t = threadIdx.x;             // 0..255
    __shared__ float s_lds[4*CS];
    __shared__ float x_lds[4*CZ];
    __shared__ float qkrow[4][2*CZ];
    __shared__ float red[4][2];
    size_t base = (size_t)blk * 4 * CS;
    for (int i = t; i < 4*CS; i += 256) s_lds[i] = s[base + i];
    __syncthreads();

    int c = t & 127, rpair = t >> 7;
    float aA = 0.f, aB = 0.f;
    {
        const float4* w4 = (const float4*)(W_s + (size_t)c * CS);
        const float4* sA = (const float4*)(s_lds + (2*rpair    )*CS);
        const float4* sB = (const float4*)(s_lds + (2*rpair + 1)*CS);
        #pragma unroll 4
        for (int i = 0; i < CS/4; ++i) {
            float4 w = w4[i];
            float4 vA = sA[i], vB = sB[i];
            aA += w.x*vA.x + w.y*vA.y + w.z*vA.z + w.w*vA.w;
            aB += w.x*vB.x + w.y*vB.y + w.z*vB.z + w.w*vB.w;
        }
    }
    {
        float sA = aA*aA, sB = aB*aB;
        wave_reduce_sum2(sA, sB);
        int lane = t & 63, wid = t >> 6;
        if (lane == 0) { red[wid][0] = sA; red[wid][1] = sB; }
    }
    __syncthreads();
    {
        float g = g_s[c];
        int w0 = (rpair == 0) ? 0 : 2;
        float tA = red[w0][0] + red[w0+1][0];
        float tB = red[w0][1] + red[w0+1][1];
        x_lds[(2*rpair  )*CZ + c] = aA * rsqrtf(tA*(1.f/CZ) + 1e-5f) * g;
        x_lds[(2*rpair+1)*CZ + c] = aB * rsqrtf(tB*(1.f/CZ) + 1e-5f) * g;
    }
    __syncthreads();

    {
        const float4* w4 = (const float4*)(W_qk + (size_t)t * CZ);
        const float4* x0 = (const float4*)(x_lds);
        const float4* x1 = (const float4*)(x_lds + CZ);
        const float4* x2 = (const float4*)(x_lds + 2*CZ);
        const float4* x3 = (const float4*)(x_lds + 3*CZ);
        float q0=0.f, q1=0.f, q2=0.f, q3=0.f;
        #pragma unroll 4
        for (int i = 0; i < CZ/4; ++i) {
            float4 w = w4[i];
            float4 v0=x0[i], v1=x1[i], v2=x2[i], v3=x3[i];
            q0 += w.x*v0.x + w.y*v0.y + w.z*v0.z + w.w*v0.w;
            q1 += w.x*v1.x + w.y*v1.y + w.z*v1.z + w.w*v1.w;
            q2 += w.x*v2.x + w.y*v2.y + w.z*v2.z + w.w*v2.w;
            q3 += w.x*v3.x + w.y*v3.y + w.z*v3.z + w.w*v3.w;
        }
        qkrow[0][t]=q0; qkrow[1][t]=q1; qkrow[2][t]=q2; qkrow[3][t]=q3;
    }
    __syncthreads();
    {
        int half = t >> 7, within = t & 127, h = within >> 4, dd = within & 15, d = dd >> 1;
        int row0 = blk * 4;
        int b = row0 >> 9;
        float inv = exp2f(-(float)(2*d) * (1.f/16.f) * 13.287712379549449f); // 10000^(-2d/16)
        #pragma unroll
        for (int r = 0; r < 4; ++r) {
            int l = (row0 + r) & (Lq - 1);
            float ang = (float)l * inv;
            float cv = cosf(ang), sn = sinf(ang);
            float xr = qkrow[r][t & ~1];
            float xi = qkrow[r][t | 1];
            float outv = (dd & 1) ? (xr*sn + xi*cv) : (xr*cv - xi*sn);
            size_t idx = ((((size_t)half*Bb + b)*Hh + h)*Lq + l)*HD + dd;
            qk_ws[idx] = outv;
        }
    }
}

// Fused softmax + output per (b,l). Gram rmsnorm precomputed (phase 1.5).
// Phase 2: wave owns a CONTIGUOUS 64-row segment, marching sequentially (HBM page locality).
__global__ __launch_bounds__(512) void k_attn(const float* __restrict__ qk_ws,
        const int* __restrict__ mask, const float* __restrict__ W_o,
        const float* __restrict__ g_z, float* __restrict__ out) {
    int row = blockIdx.x;            // b*512 + l
    int l = row & (Lq - 1);
    int b = row >> 9;
    int t = threadIdx.x;
    int w = t >> 6, lane = t & 63;
    __shared__ float p_lds[Hh][Lq];  // 16 KB softmax probs
    __shared__ float q_lds[CZ];
    __shared__ float g_lds[Hh*Hh];   // Gram matrix W_o W_o^T
    __shared__ float sc_lds[Lq];     // per-row rmsnorm scale
    if (t < CZ) {
        int qh = t >> 4, dd = t & 15;
        q_lds[t] = qk_ws[(((size_t)b*Hh + qh)*Lq + l)*HD + dd];
    }
    // Gram: wave w computes G[w][k] (k = lane&7, c-chunk = lane>>3)
    {
        int k = lane & 7, cg = lane >> 3;
        float partial = 0.f;
        #pragma unroll
        for (int cc = 0; cc < 16; ++cc) {
            int cidx = cg*16 + cc;
            partial += W_o[cidx*Hh + w] * W_o[cidx*Hh + k];
        }
        partial += __shfl_xor(partial, 8, 64);
        partial += __shfl_xor(partial, 16, 64);
        partial += __shfl_xor(partial, 32, 64);
        if (lane < 8) g_lds[w*Hh + lane] = partial;
    }
    int maskL = mask[b*Lq + l];
    __syncthreads();

    // ---- phase 1: wave w == head h softmax row ----
    {
        int h = w;
        const float* kbase = qk_ws + ((((size_t)Bb + b)*Hh + h)*Lq)*HD;
        float q[HD];
        #pragma unroll
        for (int d = 0; d < HD; ++d) q[d] = q_lds[h*HD + d];
        float sv[8];
        float mx = NEG_MAX;
        #pragma unroll
        for (int i = 0; i < 8; ++i) {
            int m = i*64 + lane;
            const float4* k4 = (const float4*)(kbase + (size_t)m * HD);
            float4 k0=k4[0], k1=k4[1], k2=k4[2], k3=k4[3];
            float acc = q[0]*k0.x + q[1]*k0.y + q[2]*k0.z + q[3]*k0.w
                      + q[4]*k1.x + q[5]*k1.y + q[6]*k1.z + q[7]*k1.w
                      + q[8]*k2.x + q[9]*k2.y + q[10]*k2.z + q[11]*k2.w
                      + q[12]*k3.x + q[13]*k3.y + q[14]*k3.z + q[15]*k3.w;
            int pm = maskL & mask[b*Lq + m];
            sv[i] = pm ? acc*0.25f : NEG_MAX;
            mx = fmaxf(mx, sv[i]);
        }
        mx = wave_reduce_max(mx);
        float e[8];
        float sum = 0.f;
        #pragma unroll
        for (int i = 0; i < 8; ++i) { e[i] = __expf(sv[i]-mx); sum += e[i]; }
        sum = wave_reduce_sum(sum);
        float inv = 1.f / sum;
        #pragma unroll
        for (int i = 0; i < 8; ++i) p_lds[h][i*64+lane] = e[i]*inv;
    }
    __syncthreads();

    // ---- phase 1.5: sc[m] = rsqrt(p^T G p / 128 + eps), thread t = row t ----
    {
        float p[8];
        #pragma unroll
        for (int k = 0; k < 8; ++k) p[k] = p_lds[k][t];
        float ss = 0.f;
        #pragma unroll
        for (int j = 0; j < 8; ++j) {
            float4 gA = *(const float4*)&g_lds[j*8];
            float4 gB = *(const float4*)&g_lds[j*8 + 4];
            float qj = gA.x*p[0] + gA.y*p[1] + gA.z*p[2] + gA.w*p[3]
                     + gB.x*p[4] + gB.y*p[5] + gB.z*p[6] + gB.w*p[7];
            ss += p[j]*qj;
        }
        sc_lds[t] = rsqrtf(ss*(1.f/CZ) + 1e-5f);
    }

    // per-lane output weights (2 ch/lane, 16 regs — proven layout)
    int c0 = lane * 2;
    float wo0[Hh], wo1[Hh];
    {
        const float4* wp = (const float4*)(W_o + (size_t)c0 * Hh);
        float4 A0=wp[0], A1=wp[1], A2=wp[2], A3=wp[3];
        wo0[0]=A0.x; wo0[1]=A0.y; wo0[2]=A0.z; wo0[3]=A0.w;
        wo0[4]=A1.x; wo0[5]=A1.y; wo0[6]=A1.z; wo0[7]=A1.w;
        wo1[0]=A2.x; wo1[1]=A2.y; wo1[2]=A2.z; wo1[3]=A2.w;
        wo1[4]=A3.x; wo1[5]=A3.y; wo1[6]=A3.z; wo1[7]=A3.w;
    }
    float gx = g_z[c0], gy = g_z[c0 + 1];
    __syncthreads();

    // ---- phase 2: wave w owns rows [w*64, w*64+64), sequential store walk ----
    float* obase = out + (size_t)row * Lq * CZ;
    #pragma unroll 1
    for (int i = 0; i < 32; ++i) {
        int m0 = w*64 + i*2;          // rows m0, m0+1 — address-sequential per wave
        float2 pp[Hh];
        #pragma unroll
        for (int k = 0; k < Hh; ++k) pp[k] = *(const float2*)&p_lds[k][m0];
        float2 sc2 = *(const float2*)&sc_lds[m0];
        float a0=0.f, b0=0.f, a1=0.f, b1=0.f;
        #pragma unroll
        for (int k = 0; k < Hh; ++k) {
            a0 += pp[k].x*wo0[k]; b0 += pp[k].x*wo1[k];
            a1 += pp[k].y*wo0[k]; b1 += pp[k].y*wo1[k];
        }
        f2_t o0; o0.x = a0*sc2.x*gx; o0.y = b0*sc2.x*gy;
        f2_t o1; o1.x = a1*sc2.y*gx; o1.y = b1*sc2.y*gy;
        __builtin_nontemporal_store(o0, (f2_t*)(obase + (size_t)m0*CZ + c0));
        __builtin_nontemporal_store(o1, (f2_t*)(obase + (size_t)(m0+1)*CZ + c0));
    }
}

extern "C" void kernel_launch(void* const* d_in, const int* in_sizes, int n_in,
                              void* d_out, int out_size, void* d_ws, size_t ws_size,
                              hipStream_t stream) {
    const float* s    = (const float*)d_in[0];
    const int*   mask = (const int*)d_in[1];
    const float* W_s  = (const float*)d_in[2];
    const float* g_s  = (const float*)d_in[3];
    const float* W_qk = (const float*)d_in[4];
    const float* W_o  = (const float*)d_in[5];
    const float* g_z  = (const float*)d_in[6];
    float* out = (float*)d_out;
    float* ws  = (float*)d_ws;

    float* qk_ws = ws;               // 2*2*8*512*16 floats = 1 MB

    k_proj<<<256, 256, 0, stream>>>(s, W_s, g_s, W_qk, qk_ws);
    k_attn<<<Bb*Lq, 512, 0, stream>>>(qk_ws, mask, W_o, g_z, out);
}